// Round 20
// baseline (197.257 us; speedup 1.0000x reference)
//
#include <hip/hip_runtime.h>
#include <cmath>
#include <cstdint>

#define B_ 64
#define L_ 2048
#define DIN 400
#define H_ 200
#define C_ 32
#define NEGBIG 1e12f
#define KC1 13   // k-chunks for GEMM-1 (K=400 -> 416)
#define NT1 13   // n-tiles for GEMM-1  (H=200 -> 208)
#define KC2 7    // k-chunks for GEMM-2 (K=208 -> 224)
#define MT2 2    // m-tiles for GEMM-2  (C=32)
#define NLC 16   // k-splits for fallback output GEMM
#define NS 16    // l-splits for fused path (128 tokens each)

typedef _Float16 half8 __attribute__((ext_vector_type(8)));
typedef float f32x4 __attribute__((ext_vector_type(4)));
typedef unsigned int uint4v __attribute__((ext_vector_type(4)));

// W / ctx pre-converted to f16 MFMA fragment layout (written by k_prep every call)
__device__ __align__(16) _Float16 g_wfrag[KC1 * NT1 * 512];  // [q][nt][lane][8]
__device__ __align__(16) _Float16 g_cfrag[KC2 * MT2 * 512];  // [q][mt][lane][8]

static __device__ __forceinline__ f32x4 mfma16(half8 a, half8 b, f32x4 c) {
  return __builtin_amdgcn_mfma_f32_16x16x32_f16(a, b, c, 0, 0, 0);
}

// tanh(v) = 1 - 2/(exp(2v)+1); exact at +/-inf, abs err ~1e-6 (f16-safe)
static __device__ __forceinline__ float fast_tanh(float v) {
  const float e = __expf(2.0f * v);
  return 1.0f - 2.0f / (e + 1.0f);
}

// ---------------------------------------------------------------------------
// Prep: convert W_proj [400,200] and context [32,200] into fragment layout.
// frag slot (q, tile, lane, j): m/n = lane&15, k = q*32 + (lane>>4)*8 + j
// ---------------------------------------------------------------------------
__global__ __launch_bounds__(64) void k_prep(const float* __restrict__ Wp,
                                             const float* __restrict__ ctx)
{
  const int lane = threadIdx.x;
  const int bid = blockIdx.x;
  if (bid < KC1 * NT1) {
    const int q = bid / NT1, nt = bid % NT1;
    const int kb = q * 32 + (lane >> 4) * 8;
    const int n  = nt * 16 + (lane & 15);
    half8 h;
#pragma unroll
    for (int j = 0; j < 8; ++j) {
      const int k = kb + j;
      const float v = (k < DIN && n < H_) ? Wp[(size_t)k * H_ + n] : 0.0f;
      h[j] = (_Float16)v;
    }
    *reinterpret_cast<half8*>(&g_wfrag[((size_t)bid << 9) + (lane << 3)]) = h;
  } else {
    const int r = bid - KC1 * NT1;
    const int c  = (r % MT2) * 16 + (lane & 15);
    const int hb = (r / MT2) * 32 + (lane >> 4) * 8;
    half8 h;
#pragma unroll
    for (int j = 0; j < 8; ++j) {
      const int hh = hb + j;
      const float v = (hh < H_) ? ctx[(size_t)c * H_ + hh] : 0.0f;
      h[j] = (_Float16)v;
    }
    *reinterpret_cast<half8*>(&g_cfrag[((size_t)r << 9) + (lane << 3)]) = h;
  }
}

// ---------------------------------------------------------------------------
// FUSED kernel v3b: 128-token splits (NS=16), arena fixed to 40960 B so the
// phase-3 xT staging [0,32000) does NOT overlap P [32000,40192).
//   [0,32000): W dbuf + proj frags (phase1, 28672 used) / xT swizzled (phase3)
//   [32000,40192): P f16 [32][128]
//   [40192,40960): redw[4][32], mfin[32], denf[32]
// 4 x 40960 = 160 KiB exactly -> 4 blocks/CU (unchanged).
// ---------------------------------------------------------------------------
__global__ __launch_bounds__(256, 4) void k_fused(
    const float* __restrict__ x,     // [B,L,DIN]
    const float* __restrict__ cb,    // [B,L,C]
    const float* __restrict__ mask,  // [B,L]
    const float* __restrict__ lam,   // [1]
    _Float16* __restrict__ O,        // [B,NS,C,DIN] f16 unnormalized partials
    float* __restrict__ stats)       // [B,NS,64]: [0,32)=m, [32,64)=den
{
  __shared__ __align__(16) unsigned char shm[40960];
  half8* smemv = reinterpret_cast<half8*>(shm);
  unsigned int* xsw = reinterpret_cast<unsigned int*>(shm);
  _Float16* Pl = reinterpret_cast<_Float16*>(shm + 32000);  // [32][128]
  float* redw  = reinterpret_cast<float*>(shm + 40192);     // [4][32]
  float* mfin  = reinterpret_cast<float*>(shm + 40704);     // [32]
  float* denf  = reinterpret_cast<float*>(shm + 40832);     // [32]

  const int tid  = threadIdx.x;
  const int lane = tid & 63;
  const int w    = __builtin_amdgcn_readfirstlane(tid >> 6);
  const int b    = blockIdx.y;
  const int split = blockIdx.x;
  const int l0   = split * 128;
  const int oct  = lane >> 4;
  const int tok  = (w << 4) | (lane & 15);   // local token within a sub-tile
  const int cq   = oct << 2;
  int cidx[8];
#pragma unroll
  for (int r = 0; r < 8; ++r) cidx[r] = (r < 4) ? (cq + r) : (16 + cq + r - 4);
  const float lamv = lam[0];

  float sv2[2][8];

  // ============ Phase 1 (x2): GEMM-1 + GEMM-2 + bias/mask ============
  for (int sub = 0; sub < 2; ++sub) {
    if (sub) __syncthreads();   // prior GEMM-2 proj-frag reads done

    f32x4 acc[NT1];
#pragma unroll
    for (int nt = 0; nt < NT1; ++nt) acc[nt] = f32x4{0.f, 0.f, 0.f, 0.f};

    const float* xrow =
        x + ((size_t)b * L_ + l0 + sub * 64 + w * 16 + (lane & 15)) * DIN + oct * 8;

    for (int i = w; i < NT1; i += 4) {
      const _Float16* gp = g_wfrag + (((size_t)i) << 9) + (lane << 3);
      __builtin_amdgcn_global_load_lds(
          (const __attribute__((address_space(1))) void*)gp,
          (__attribute__((address_space(3))) void*)(smemv + i * 64),
          16, 0, 0);
    }
    __builtin_amdgcn_sched_barrier(0);
    float4 cur0 = *reinterpret_cast<const float4*>(xrow);
    float4 cur1 = *reinterpret_cast<const float4*>(xrow + 4);

#pragma unroll
    for (int q = 0; q < KC1; ++q) {
      asm volatile("s_waitcnt vmcnt(2)\n\ts_barrier" ::: "memory");

      float4 nx0 = float4{0.f, 0.f, 0.f, 0.f};
      float4 nx1 = float4{0.f, 0.f, 0.f, 0.f};
      if (q < KC1 - 1) {
        const int nb = ((q + 1) & 1) * 832;
        for (int i = w; i < NT1; i += 4) {
          const _Float16* gp =
              g_wfrag + (((size_t)((q + 1) * NT1 + i)) << 9) + (lane << 3);
          __builtin_amdgcn_global_load_lds(
              (const __attribute__((address_space(1))) void*)gp,
              (__attribute__((address_space(3))) void*)(smemv + nb + i * 64),
              16, 0, 0);
        }
        __builtin_amdgcn_sched_barrier(0);
        const int k0 = (q + 1) * 32 + oct * 8;
        if (k0 + 7 < DIN) {
          nx0 = *reinterpret_cast<const float4*>(xrow + (q + 1) * 32);
          nx1 = *reinterpret_cast<const float4*>(xrow + (q + 1) * 32 + 4);
        }
      }

      float fa[8] = {cur0.x, cur0.y, cur0.z, cur0.w,
                     cur1.x, cur1.y, cur1.z, cur1.w};
      half8 ah;
#pragma unroll
      for (int j = 0; j < 8; ++j) ah[j] = (_Float16)fa[j];

      const int base = (q & 1) * 832;
      __builtin_amdgcn_s_setprio(1);
#pragma unroll
      for (int nt = 0; nt < NT1; ++nt) {
        const half8 bh = smemv[base + nt * 64 + lane];
        acc[nt] = mfma16(ah, bh, acc[nt]);
      }
      __builtin_amdgcn_s_setprio(0);
      cur0 = nx0;
      cur1 = nx1;
    }

    // ---- tanh + proj frags + GEMM-2 ----
    __syncthreads();
    if (lane >= 32) {
      half8 z = {};
      smemv[(24 + w) * 64 + lane] = z;
    }
    _Float16* Pp = reinterpret_cast<_Float16*>(shm);
#pragma unroll
    for (int nt = 0; nt < NT1; ++nt) {
      const int h   = nt * 16 + (lane & 15);
      const int q2  = h >> 5;
      const int lpw = ((h >> 3) & 3) << 4;
      const int jj  = h & 7;
#pragma unroll
      for (int reg = 0; reg < 4; ++reg) {
        const int t = oct * 4 + reg;
        const float p = fast_tanh(acc[nt][reg]);
        Pp[(size_t)(((q2 * 4 + w) * 64) + lpw + t) * 8 + jj] = (_Float16)p;
      }
    }

    f32x4 s0 = f32x4{0.f, 0.f, 0.f, 0.f};
    f32x4 s1 = f32x4{0.f, 0.f, 0.f, 0.f};
    __builtin_amdgcn_s_setprio(1);
#pragma unroll
    for (int q2 = 0; q2 < KC2; ++q2) {
      const half8 pb = smemv[(q2 * 4 + w) * 64 + lane];
      const half8 c0 = *reinterpret_cast<const half8*>(
          g_cfrag + (((size_t)(q2 * 2)) << 9) + (lane << 3));
      const half8 c1 = *reinterpret_cast<const half8*>(
          g_cfrag + (((size_t)(q2 * 2 + 1)) << 9) + (lane << 3));
      s0 = mfma16(c0, pb, s0);
      s1 = mfma16(c1, pb, s1);
    }
    __builtin_amdgcn_s_setprio(0);

    const size_t bl = (size_t)b * L_ + l0 + sub * 64 + tok;
    const float mk = (1.0f - mask[bl]) * NEGBIG;
    const float4 cb0 = *reinterpret_cast<const float4*>(cb + bl * C_ + cq);
    const float4 cb1 = *reinterpret_cast<const float4*>(cb + bl * C_ + 16 + cq);
    sv2[sub][0] = s0[0] + lamv * cb0.x - mk;
    sv2[sub][1] = s0[1] + lamv * cb0.y - mk;
    sv2[sub][2] = s0[2] + lamv * cb0.z - mk;
    sv2[sub][3] = s0[3] + lamv * cb0.w - mk;
    sv2[sub][4] = s1[0] + lamv * cb1.x - mk;
    sv2[sub][5] = s1[1] + lamv * cb1.y - mk;
    sv2[sub][6] = s1[2] + lamv * cb1.z - mk;
    sv2[sub][7] = s1[3] + lamv * cb1.w - mk;
  }

  // ================= Phase 2: softmax over 128 tokens =================
  float mx[8];
#pragma unroll
  for (int r = 0; r < 8; ++r) {
    float v = fmaxf(sv2[0][r], sv2[1][r]);
#pragma unroll
    for (int off = 1; off < 16; off <<= 1) v = fmaxf(v, __shfl_xor(v, off));
    mx[r] = v;
  }
  if ((lane & 15) == 0) {
#pragma unroll
    for (int r = 0; r < 8; ++r) redw[w * 32 + cidx[r]] = mx[r];
  }
  __syncthreads();
  if (tid < 32)
    mfin[tid] = fmaxf(fmaxf(redw[tid], redw[32 + tid]),
                      fmaxf(redw[64 + tid], redw[96 + tid]));
  __syncthreads();

  // P = exp(s - m) -> Pl[c][128] (r15 swizzle per 64-token sub); den partial
  float pd[8];
#pragma unroll
  for (int r = 0; r < 8; ++r) {
    const int c = cidx[r];
    const int slot = c * 128 + ((((tok >> 3) ^ (c & 7)) & 7) << 3) + (tok & 7);
    const float p0 = __expf(sv2[0][r] - mfin[c]);
    const float p1 = __expf(sv2[1][r] - mfin[c]);
    Pl[slot]      = (_Float16)p0;
    Pl[slot + 64] = (_Float16)p1;
    pd[r] = p0 + p1;
  }
#pragma unroll
  for (int r = 0; r < 8; ++r) {
    float v = pd[r];
#pragma unroll
    for (int off = 1; off < 16; off <<= 1) v += __shfl_xor(v, off);
    pd[r] = v;
  }
  if ((lane & 15) == 0) {
#pragma unroll
    for (int r = 0; r < 8; ++r) redw[w * 32 + cidx[r]] = pd[r];
  }
  __syncthreads();
  if (tid < 32)
    denf[tid] = redw[tid] + redw[32 + tid] + redw[64 + tid] + redw[96 + tid];

  // ================= Phase 3: PV over 4 x 32-token halves =================
  const int ntile0w = (w == 0) ? 0 : (1 + 6 * w);   // 7,6,6,6 of 25 d-tiles
  const int NTWv   = w ? 6 : 7;
  const int n   = lane & 15;

  f32x4 oacc[2][7];
#pragma unroll
  for (int ct = 0; ct < 2; ++ct)
#pragma unroll
    for (int nt = 0; nt < 7; ++nt) oacc[ct][nt] = f32x4{0.f, 0.f, 0.f, 0.f};

  const float* xb = x + ((size_t)b * L_ + l0) * DIN;

  for (int h = 0; h < 4; ++h) {
    __syncthreads();  // prior phase reads of xsw region done
    // stage xT for tokens [h*32, h*32+32): stride-20, proven swizzle
    for (int s = 0; s < 7; ++s) {
      const int i = s * 256 + tid;
      if (i < 1600) {
        const int lp = i / 100, qd = i - lp * 100;
        const float* src = xb + (size_t)(h * 32 + 2 * lp) * DIN + 4 * qd;
        const float4 r0 = *reinterpret_cast<const float4*>(src);
        const float4 r1 = *reinterpret_cast<const float4*>(src + DIN);
#pragma unroll
        for (int k = 0; k < 4; ++k) {
          const int d = 4 * qd + k;
          const int sw = ((d >> 2) ^ (d >> 4)) & 3;
          const int col = (((lp >> 2) ^ sw) << 2) | (lp & 3);
          const _Float16 h0 = (_Float16)r0[k];
          const _Float16 h1 = (_Float16)r1[k];
          unsigned int pk = (unsigned int)__builtin_bit_cast(unsigned short, h0) |
                            ((unsigned int)__builtin_bit_cast(unsigned short, h1) << 16);
          xsw[d * 20 + col] = pk;
        }
      }
    }
    __syncthreads();

    // A-frags from Pl: sub = h>>1, kblk = ((h&1)<<2)|oct
    const int sub = h >> 1;
    const int kblk = ((h & 1) << 2) | oct;
    half8 aP[2];
#pragma unroll
    for (int ct = 0; ct < 2; ++ct) {
      const int c = ct * 16 + n;
      aP[ct] = *reinterpret_cast<const half8*>(
          &Pl[c * 128 + sub * 64 + (((kblk ^ (c & 7)) & 7) << 3)]);
    }
    __builtin_amdgcn_s_setprio(1);
#pragma unroll
    for (int nt = 0; nt < 7; ++nt) {
      if (nt < NTWv) {
        const int d0 = (ntile0w + nt) * 16 + n;
        const int sw = ((d0 >> 2) ^ (d0 >> 4)) & 3;
        const half8 bh = *reinterpret_cast<const half8*>(
            &xsw[d0 * 20 + ((oct ^ sw) << 2)]);
        oacc[0][nt] = mfma16(aP[0], bh, oacc[0][nt]);
        oacc[1][nt] = mfma16(aP[1], bh, oacc[1][nt]);
      }
    }
    __builtin_amdgcn_s_setprio(0);
  }

  // ---- epilogue: O f16 partials + stats ----
  _Float16* Ob = O + ((size_t)(b * NS + split) * C_) * DIN;
#pragma unroll
  for (int nt = 0; nt < 7; ++nt) {
    if (nt < NTWv) {
      const int d = (ntile0w + nt) * 16 + n;
#pragma unroll
      for (int ct = 0; ct < 2; ++ct) {
#pragma unroll
        for (int reg = 0; reg < 4; ++reg) {
          const int c = ct * 16 + oct * 4 + reg;
          Ob[(size_t)c * DIN + d] = (_Float16)oacc[ct][nt][reg];
        }
      }
    }
  }
  if (tid < 32) {
    float* st = stats + (size_t)(b * NS + split) * 64;
    st[tid]      = mfin[tid];
    st[32 + tid] = denf[tid];
  }
}

// ---------------------------------------------------------------------------
// Combine: out[b,c,d] = sum_s e^{m_s-M} O_s[c,d] / sum_s e^{m_s-M} den_s
// ---------------------------------------------------------------------------
__global__ __launch_bounds__(256) void k_combine(
    const _Float16* __restrict__ O, const float* __restrict__ stats,
    float* __restrict__ out)
{
  const int idx = blockIdx.x * 256 + threadIdx.x;   // B*C*50 = 102400
  const int b  = idx / (C_ * 50);
  const int rm = idx - b * (C_ * 50);
  const int c  = rm / 50;
  const int dq = rm - c * 50;

  const float* st = stats + (size_t)b * NS * 64;
  float M = -3.4e38f;
#pragma unroll
  for (int s = 0; s < NS; ++s) M = fmaxf(M, st[s * 64 + c]);
  float wsc[NS];
  float denom = 0.f;
#pragma unroll
  for (int s = 0; s < NS; ++s) {
    const float e = __expf(st[s * 64 + c] - M);
    wsc[s] = e;
    denom += e * st[s * 64 + 32 + c];
  }
  const float inv = 1.0f / denom;

  float o[8] = {};
  const uint4v* Op = reinterpret_cast<const uint4v*>(
      O + ((size_t)(b * NS) * C_ + c) * DIN + dq * 8);
#pragma unroll
  for (int s = 0; s < NS; ++s) {
    const uint4v v = Op[(size_t)s * (C_ * DIN / 8)];
#pragma unroll
    for (int j = 0; j < 4; ++j) {
      o[2 * j]     += wsc[s] * (float)__builtin_bit_cast(_Float16, (unsigned short)(v[j] & 0xffff));
      o[2 * j + 1] += wsc[s] * (float)__builtin_bit_cast(_Float16, (unsigned short)(v[j] >> 16));
    }
  }
  float* op = out + ((size_t)(b * C_) + c) * DIN + dq * 8;
  *reinterpret_cast<float4*>(op)     = float4{o[0]*inv, o[1]*inv, o[2]*inv, o[3]*inv};
  *reinterpret_cast<float4*>(op + 4) = float4{o[4]*inv, o[5]*inv, o[6]*inv, o[7]*inv};
}

// ======================= FALLBACK PATH (r14, proven) =======================
__global__ __launch_bounds__(256, 5) void k_scores(
    const float* __restrict__ x, const float* __restrict__ cb,
    const float* __restrict__ mask, const float* __restrict__ lam,
    float* __restrict__ S)
{
  __shared__ half8 smemv[1792];
  const int tid  = threadIdx.x;
  const int lane = tid & 63;
  const int w    = __builtin_amdgcn_readfirstlane(tid >> 6);
  const int b    = blockIdx.y;
  const int l0   = blockIdx.x * 64;
  const int oct  = lane >> 4;

  f32x4 acc[NT1];
#pragma unroll
  for (int nt = 0; nt < NT1; ++nt) acc[nt] = f32x4{0.f, 0.f, 0.f, 0.f};
  const float* xrow =
      x + ((size_t)b * L_ + l0 + w * 16 + (lane & 15)) * DIN + oct * 8;
  for (int i = w; i < NT1; i += 4) {
    const _Float16* gp = g_wfrag + (((size_t)i) << 9) + (lane << 3);
    __builtin_amdgcn_global_load_lds(
        (const __attribute__((address_space(1))) void*)gp,
        (__attribute__((address_space(3))) void*)(smemv + i * 64), 16, 0, 0);
  }
  __builtin_amdgcn_sched_barrier(0);
  float4 cur0 = *reinterpret_cast<const float4*>(xrow);
  float4 cur1 = *reinterpret_cast<const float4*>(xrow + 4);
#pragma unroll
  for (int q = 0; q < KC1; ++q) {
    asm volatile("s_waitcnt vmcnt(2)\n\ts_barrier" ::: "memory");
    float4 nx0 = float4{0.f, 0.f, 0.f, 0.f};
    float4 nx1 = float4{0.f, 0.f, 0.f, 0.f};
    if (q < KC1 - 1) {
      const int nb = ((q + 1) & 1) * 832;
      for (int i = w; i < NT1; i += 4) {
        const _Float16* gp =
            g_wfrag + (((size_t)((q + 1) * NT1 + i)) << 9) + (lane << 3);
        __builtin_amdgcn_global_load_lds(
            (const __attribute__((address_space(1))) void*)gp,
            (__attribute__((address_space(3))) void*)(smemv + nb + i * 64),
            16, 0, 0);
      }
      __builtin_amdgcn_sched_barrier(0);
      const int k0 = (q + 1) * 32 + oct * 8;
      if (k0 + 7 < DIN) {
        nx0 = *reinterpret_cast<const float4*>(xrow + (q + 1) * 32);
        nx1 = *reinterpret_cast<const float4*>(xrow + (q + 1) * 32 + 4);
      }
    }
    float fa[8] = {cur0.x, cur0.y, cur0.z, cur0.w,
                   cur1.x, cur1.y, cur1.z, cur1.w};
    half8 ah;
#pragma unroll
    for (int j = 0; j < 8; ++j) ah[j] = (_Float16)fa[j];
    const int base = (q & 1) * 832;
#pragma unroll
    for (int nt = 0; nt < NT1; ++nt) {
      const half8 bh = smemv[base + nt * 64 + lane];
      acc[nt] = mfma16(ah, bh, acc[nt]);
    }
    cur0 = nx0; cur1 = nx1;
  }
  __syncthreads();
  if (lane >= 32) { half8 z = {}; smemv[(24 + w) * 64 + lane] = z; }
  _Float16* Pp = reinterpret_cast<_Float16*>(smemv);
#pragma unroll
  for (int nt = 0; nt < NT1; ++nt) {
    const int h = nt * 16 + (lane & 15);
    const int q2 = h >> 5, lpw = ((h >> 3) & 3) << 4, jj = h & 7;
#pragma unroll
    for (int reg = 0; reg < 4; ++reg) {
      const int t = ((lane >> 4) << 2) + reg;
      Pp[(size_t)(((q2 * 4 + w) * 64) + lpw + t) * 8 + jj] =
          (_Float16)fast_tanh(acc[nt][reg]);
    }
  }
  f32x4 s0 = f32x4{0.f, 0.f, 0.f, 0.f};
  f32x4 s1 = f32x4{0.f, 0.f, 0.f, 0.f};
#pragma unroll
  for (int q2 = 0; q2 < KC2; ++q2) {
    const half8 pb = smemv[(q2 * 4 + w) * 64 + lane];
    const half8 c0 = *reinterpret_cast<const half8*>(
        g_cfrag + (((size_t)(q2 * 2)) << 9) + (lane << 3));
    const half8 c1 = *reinterpret_cast<const half8*>(
        g_cfrag + (((size_t)(q2 * 2 + 1)) << 9) + (lane << 3));
    s0 = mfma16(c0, pb, s0);
    s1 = mfma16(c1, pb, s1);
  }
  const int tok = (w << 4) | (lane & 15);
  const size_t bl = (size_t)b * L_ + l0 + tok;
  const float lamv = lam[0];
  const float mk = (1.0f - mask[bl]) * NEGBIG;
  const int cq = (lane >> 4) << 2;
  const float4 cb0 = *reinterpret_cast<const float4*>(cb + bl * C_ + cq);
  const float4 cb1 = *reinterpret_cast<const float4*>(cb + bl * C_ + 16 + cq);
  float* Sp = S + (size_t)b * C_ * L_ + l0 + tok;
  Sp[(size_t)(cq + 0) * L_] = s0[0] + lamv * cb0.x - mk;
  Sp[(size_t)(cq + 1) * L_] = s0[1] + lamv * cb0.y - mk;
  Sp[(size_t)(cq + 2) * L_] = s0[2] + lamv * cb0.z - mk;
  Sp[(size_t)(cq + 3) * L_] = s0[3] + lamv * cb0.w - mk;
  Sp[(size_t)(16 + cq + 0) * L_] = s1[0] + lamv * cb1.x - mk;
  Sp[(size_t)(16 + cq + 1) * L_] = s1[1] + lamv * cb1.y - mk;
  Sp[(size_t)(16 + cq + 2) * L_] = s1[2] + lamv * cb1.z - mk;
  Sp[(size_t)(16 + cq + 3) * L_] = s1[3] + lamv * cb1.w - mk;
}

__global__ __launch_bounds__(256) void k_softmax(float* __restrict__ S,
                                                 _Float16* __restrict__ wh)
{
  const int row = blockIdx.x;
  float* R = S + (size_t)row * L_;
  const int t8 = threadIdx.x * 8;
  const float4 va = *reinterpret_cast<const float4*>(R + t8);
  const float4 vb = *reinterpret_cast<const float4*>(R + t8 + 4);
  float v[8] = {va.x, va.y, va.z, va.w, vb.x, vb.y, vb.z, vb.w};
  float m = -3.4e38f;
#pragma unroll
  for (int j = 0; j < 8; ++j) m = fmaxf(m, v[j]);
#pragma unroll
  for (int o = 32; o > 0; o >>= 1) m = fmaxf(m, __shfl_xor(m, o));
  __shared__ float red[4];
  const int wid = threadIdx.x >> 6;
  if ((threadIdx.x & 63) == 0) red[wid] = m;
  __syncthreads();
  m = fmaxf(fmaxf(red[0], red[1]), fmaxf(red[2], red[3]));
  __syncthreads();
  float s = 0.f;
#pragma unroll
  for (int j = 0; j < 8; ++j) { v[j] = __expf(v[j] - m); s += v[j]; }
#pragma unroll
  for (int o = 32; o > 0; o >>= 1) s += __shfl_xor(s, o);
  if ((threadIdx.x & 63) == 0) red[wid] = s;
  __syncthreads();
  s = red[0] + red[1] + red[2] + red[3];
  const float inv = 1.0f / s;
  if (wh != nullptr) {
    uint4v pk;
#pragma unroll
    for (int p = 0; p < 4; ++p) {
      const _Float16 h0 = (_Float16)(v[2 * p] * inv);
      const _Float16 h1 = (_Float16)(v[2 * p + 1] * inv);
      pk[p] = (unsigned int)__builtin_bit_cast(unsigned short, h0) |
              ((unsigned int)__builtin_bit_cast(unsigned short, h1) << 16);
    }
    *reinterpret_cast<uint4v*>(wh + (size_t)row * L_ + t8) = pk;
  } else {
#pragma unroll
    for (int j = 0; j < 8; ++j) R[t8 + j] = v[j] * inv;
  }
}

__global__ __launch_bounds__(512, 4) void k_out_mfma(
    const float* __restrict__ x, const _Float16* __restrict__ wh,
    _Float16* __restrict__ part)
{
  __shared__ unsigned int xsw[400 * 20];
  __shared__ unsigned int ws16[32][16];
  const int tid  = threadIdx.x;
  const int lane = tid & 63;
  const int w    = __builtin_amdgcn_readfirstlane(tid >> 6);
  const int b    = blockIdx.y;
  const int kq   = blockIdx.x;
  const int l0b  = kq * (L_ / NLC);
  const int ntile0 = (w < 7) ? w * 3 : 21;
  const int NTW    = (w < 7) ? 3 : 4;
  const int n   = lane & 15;
  const int oct = lane >> 4;
  f32x4 acc[4][2];
#pragma unroll
  for (int i = 0; i < 4; ++i) {
    acc[i][0] = f32x4{0.f, 0.f, 0.f, 0.f};
    acc[i][1] = f32x4{0.f, 0.f, 0.f, 0.f};
  }
  const float* xb = x + ((size_t)b * L_ + l0b) * DIN;
  const unsigned int* whb = reinterpret_cast<const unsigned int*>(
      wh + (size_t)b * C_ * L_ + l0b);
  float4 r0[4], r1[4];
  unsigned int wreg;
#pragma unroll
  for (int s = 0; s < 4; ++s) {
    const int i = s * 512 + tid;
    if (s < 3 || i < 1600) {
      const int lp = i / 100, qd = i - lp * 100;
      const float* src = xb + (size_t)(2 * lp) * DIN + 4 * qd;
      r0[s] = *reinterpret_cast<const float4*>(src);
      r1[s] = *reinterpret_cast<const float4*>(src + DIN);
    }
  }
  wreg = whb[((size_t)(tid >> 4) * L_) / 2 + (tid & 15)];
  const int NCH = (L_ / NLC) / 32;
  for (int ch = 0; ch < NCH; ++ch) {
    __syncthreads();
#pragma unroll
    for (int s = 0; s < 4; ++s) {
      const int i = s * 512 + tid;
      if (s < 3 || i < 1600) {
        const int lp = i / 100, qd = i - lp * 100;
#pragma unroll
        for (int k = 0; k < 4; ++k) {
          const int d = 4 * qd + k;
          const int sw = ((d >> 2) ^ (d >> 4)) & 3;
          const int col = (((lp >> 2) ^ sw) << 2) | (lp & 3);
          const _Float16 h0 = (_Float16)r0[s][k];
          const _Float16 h1 = (_Float16)r1[s][k];
          unsigned int pk = (unsigned int)__builtin_bit_cast(unsigned short, h0) |
                            ((unsigned int)__builtin_bit_cast(unsigned short, h1) << 16);
          xsw[d * 20 + col] = pk;
        }
      }
    }
    ws16[tid >> 4][tid & 15] = wreg;
    __syncthreads();
    if (ch + 1 < NCH) {
      const float* xc = xb + (size_t)((ch + 1) * 32) * DIN;
#pragma unroll
      for (int s = 0; s < 4; ++s) {
        const int i = s * 512 + tid;
        if (s < 3 || i < 1600) {
          const int lp = i / 100, qd = i - lp * 100;
          const float* src = xc + (size_t)(2 * lp) * DIN + 4 * qd;
          r0[s] = *reinterpret_cast<const float4*>(src);
          r1[s] = *reinterpret_cast<const float4*>(src + DIN);
        }
      }
      wreg = whb[((size_t)(tid >> 4) * L_ + (ch + 1) * 32) / 2 + (tid & 15)];
    }
    union { uint4v u; half8 h; } a0c, a1c;
    a0c.u = *reinterpret_cast<const uint4v*>(&ws16[n][oct * 4]);
    a1c.u = *reinterpret_cast<const uint4v*>(&ws16[n + 16][oct * 4]);
    const half8 a0 = a0c.h;
    const half8 a1 = a1c.h;
#pragma unroll
    for (int nt = 0; nt < 4; ++nt) {
      if (nt < NTW) {
        const int d0 = (ntile0 + nt) * 16 + n;
        const int sw = ((d0 >> 2) ^ (d0 >> 4)) & 3;
        const half8 bh = *reinterpret_cast<const half8*>(
            &xsw[d0 * 20 + ((oct ^ sw) << 2)]);
        acc[nt][0] = mfma16(a0, bh, acc[nt][0]);
        acc[nt][1] = mfma16(a1, bh, acc[nt][1]);
      }
    }
  }
  _Float16* pb = part + ((size_t)(b * NLC + kq) * C_) * DIN;
#pragma unroll
  for (int nt = 0; nt < 4; ++nt) {
    if (nt < NTW) {
      const int d = (ntile0 + nt) * 16 + n;
#pragma unroll
      for (int mt = 0; mt < 2; ++mt) {
#pragma unroll
        for (int reg = 0; reg < 4; ++reg) {
          const int c = mt * 16 + oct * 4 + reg;
          pb[(size_t)c * DIN + d] = (_Float16)acc[nt][mt][reg];
        }
      }
    }
  }
}

__global__ __launch_bounds__(256) void k_out_reduce(
    const _Float16* __restrict__ part, float* __restrict__ out)
{
  const int idx = blockIdx.x * 256 + threadIdx.x;
  const int per_b = C_ * DIN / 8;
  const int b = idx / per_b;
  const int r = idx - b * per_b;
  const uint4v* p = reinterpret_cast<const uint4v*>(part) +
                    (size_t)b * NLC * per_b + r;
  float s[8] = {};
#pragma unroll
  for (int lc = 0; lc < NLC; ++lc) {
    const uint4v v = p[(size_t)lc * per_b];
#pragma unroll
    for (int j = 0; j < 4; ++j) {
      s[2 * j]     += (float)__builtin_bit_cast(_Float16, (unsigned short)(v[j] & 0xffff));
      s[2 * j + 1] += (float)__builtin_bit_cast(_Float16, (unsigned short)(v[j] >> 16));
    }
  }
  float* o = out + (size_t)idx * 8;
  *reinterpret_cast<float4*>(o)     = float4{s[0], s[1], s[2], s[3]};
  *reinterpret_cast<float4*>(o + 4) = float4{s[4], s[5], s[6], s[7]};
}

extern "C" void kernel_launch(void* const* d_in, const int* in_sizes, int n_in,
                              void* d_out, int out_size, void* d_ws, size_t ws_size,
                              hipStream_t stream)
{
  const float* x    = (const float*)d_in[0];
  const float* cb   = (const float*)d_in[1];
  const float* mask = (const float*)d_in[2];
  const float* Wp   = (const float*)d_in[3];
  const float* ctx  = (const float*)d_in[4];
  const float* lam  = (const float*)d_in[5];
  float* out = (float*)d_out;

  k_prep<<<dim3(KC1 * NT1 + KC2 * MT2), 64, 0, stream>>>(Wp, ctx);

  // fused path: O [B,NS,C,DIN] f16 (26.2 MB) + stats [B,NS,64] f32 (0.26 MB)
  const size_t O_bytes = (size_t)B_ * NS * C_ * DIN * sizeof(_Float16);
  const size_t st_bytes = (size_t)B_ * NS * 64 * sizeof(float);
  if (ws_size >= O_bytes + st_bytes) {
    _Float16* O = (_Float16*)d_ws;
    float* stats = (float*)((char*)d_ws + O_bytes);
    k_fused<<<dim3(NS, B_), 256, 0, stream>>>(x, cb, mask, lam, O, stats);
    k_combine<<<dim3(B_ * C_ * 50 / 256), 256, 0, stream>>>(O, stats, out);
    return;
  }

  // fallback: proven r14 5-kernel path (needs 34.6 MB)
  const size_t part_bytes = (size_t)B_ * NLC * C_ * DIN * sizeof(_Float16);
  float* S = (float*)d_ws;
  _Float16* part = (_Float16*)d_ws;
  _Float16* wh = (_Float16*)((char*)d_ws + part_bytes);
  k_scores<<<dim3(L_ / 64, B_), 256, 0, stream>>>(x, cb, mask, lam, S);
  k_softmax<<<dim3(B_ * C_), 256, 0, stream>>>(S, wh);
  k_out_mfma<<<dim3(NLC, B_), 512, 0, stream>>>(x, wh, part);
  k_out_reduce<<<dim3(B_ * C_ * DIN / 8 / 256), 256, 0, stream>>>(part, out);
}

// Round 21
// 100.975 us; speedup vs baseline: 1.9535x; 1.9535x over previous
//
#include <hip/hip_runtime.h>
#include <cmath>
#include <cstdint>

#define B_ 64
#define L_ 2048
#define DIN 400
#define H_ 200
#define C_ 32
#define NEGBIG 1e12f
#define KC1 13   // k-chunks for GEMM-1 (K=400 -> 416)
#define NT1 13   // n-tiles for GEMM-1  (H=200 -> 208)
#define KC2 7    // k-chunks for GEMM-2 (K=208 -> 224)
#define MT2 2    // m-tiles for GEMM-2  (C=32)
#define NLC 16   // k-splits for fallback output GEMM
#define NS 32    // l-splits for fused path (64 tokens each)

typedef _Float16 half8 __attribute__((ext_vector_type(8)));
typedef float f32x4 __attribute__((ext_vector_type(4)));
typedef unsigned int uint4v __attribute__((ext_vector_type(4)));

// W / ctx pre-converted to f16 MFMA fragment layout (written by k_prep every call)
__device__ __align__(16) _Float16 g_wfrag[KC1 * NT1 * 512];  // [q][nt][lane][8]
__device__ __align__(16) _Float16 g_cfrag[KC2 * MT2 * 512];  // [q][mt][lane][8]

static __device__ __forceinline__ f32x4 mfma16(half8 a, half8 b, f32x4 c) {
  return __builtin_amdgcn_mfma_f32_16x16x32_f16(a, b, c, 0, 0, 0);
}

// tanh(v) = 1 - 2/(exp(2v)+1); exact at +/-inf, abs err ~1e-6 (f16-safe)
static __device__ __forceinline__ float fast_tanh(float v) {
  const float e = __expf(2.0f * v);
  return 1.0f - 2.0f / (e + 1.0f);
}

// ---------------------------------------------------------------------------
// Prep: convert W_proj [400,200] and context [32,200] into fragment layout.
// frag slot (q, tile, lane, j): m/n = lane&15, k = q*32 + (lane>>4)*8 + j
// ---------------------------------------------------------------------------
__global__ __launch_bounds__(64) void k_prep(const float* __restrict__ Wp,
                                             const float* __restrict__ ctx)
{
  const int lane = threadIdx.x;
  const int bid = blockIdx.x;
  if (bid < KC1 * NT1) {
    const int q = bid / NT1, nt = bid % NT1;
    const int kb = q * 32 + (lane >> 4) * 8;
    const int n  = nt * 16 + (lane & 15);
    half8 h;
#pragma unroll
    for (int j = 0; j < 8; ++j) {
      const int k = kb + j;
      const float v = (k < DIN && n < H_) ? Wp[(size_t)k * H_ + n] : 0.0f;
      h[j] = (_Float16)v;
    }
    *reinterpret_cast<half8*>(&g_wfrag[((size_t)bid << 9) + (lane << 3)]) = h;
  } else {
    const int r = bid - KC1 * NT1;
    const int c  = (r % MT2) * 16 + (lane & 15);
    const int hb = (r / MT2) * 32 + (lane >> 4) * 8;
    half8 h;
#pragma unroll
    for (int j = 0; j < 8; ++j) {
      const int hh = hb + j;
      const float v = (hh < H_) ? ctx[(size_t)c * H_ + hh] : 0.0f;
      h[j] = (_Float16)v;
    }
    *reinterpret_cast<half8*>(&g_cfrag[((size_t)r << 9) + (lane << 3)]) = h;
  }
}

// ---------------------------------------------------------------------------
// FUSED kernel (r18 best, verbatim): per block = one (b, 64-token split).
// Phase 1: GEMM-1 + GEMM-2 + bias/mask (v7 code, scores stay in registers)
// Phase 2: split-local softmax (shuffle + LDS reduce) -> m[c], den[c]
// Phase 3: P = exp(s-m) -> LDS (swizzle (tok>>3)^(c&7));  x re-read staged
//          transposed f16 (stride-20 proven scheme), PV MFMA -> O f16 + stats
// T5 setprio around MFMA clusters (r18: neutral-positive).
// ---------------------------------------------------------------------------
__global__ __launch_bounds__(256, 4) void k_fused(
    const float* __restrict__ x,     // [B,L,DIN]
    const float* __restrict__ cb,    // [B,L,C]
    const float* __restrict__ mask,  // [B,L]
    const float* __restrict__ lam,   // [1]
    _Float16* __restrict__ O,        // [B,NS,C,DIN] f16 unnormalized partials
    float* __restrict__ stats)       // [B,NS,64]: [0,32)=m, [32,64)=den
{
  // one aliased LDS arena, 38144 B:
  //  [0,28672): W dbuf (phase1) / proj frags (phase1b) / xT swizzled (phase3)
  //  [32768,36864): P f16 [32][64] swizzled
  //  [36864,38144): reduce scratch: redw [4*32] f32, mfin[32], denf[32]
  __shared__ __align__(16) unsigned char shm[38144];
  half8* smemv = reinterpret_cast<half8*>(shm);
  unsigned int* xsw = reinterpret_cast<unsigned int*>(shm);
  _Float16* Pl = reinterpret_cast<_Float16*>(shm + 32768);
  float* redw  = reinterpret_cast<float*>(shm + 36864);  // [4][32]
  float* mfin  = reinterpret_cast<float*>(shm + 37376);  // [32]
  float* denf  = reinterpret_cast<float*>(shm + 37504);  // [32]

  const int tid  = threadIdx.x;
  const int lane = tid & 63;
  const int w    = __builtin_amdgcn_readfirstlane(tid >> 6);
  const int b    = blockIdx.y;
  const int split = blockIdx.x;
  const int l0   = split * 64;
  const int oct  = lane >> 4;

  // ================= Phase 1: GEMM-1 (v7 verbatim) =================
  f32x4 acc[NT1];
#pragma unroll
  for (int nt = 0; nt < NT1; ++nt) acc[nt] = f32x4{0.f, 0.f, 0.f, 0.f};

  const float* xrow =
      x + ((size_t)b * L_ + l0 + w * 16 + (lane & 15)) * DIN + oct * 8;

  for (int i = w; i < NT1; i += 4) {
    const _Float16* gp = g_wfrag + (((size_t)i) << 9) + (lane << 3);
    __builtin_amdgcn_global_load_lds(
        (const __attribute__((address_space(1))) void*)gp,
        (__attribute__((address_space(3))) void*)(smemv + i * 64),
        16, 0, 0);
  }
  __builtin_amdgcn_sched_barrier(0);
  float4 cur0 = *reinterpret_cast<const float4*>(xrow);
  float4 cur1 = *reinterpret_cast<const float4*>(xrow + 4);

#pragma unroll
  for (int q = 0; q < KC1; ++q) {
    asm volatile("s_waitcnt vmcnt(2)\n\ts_barrier" ::: "memory");

    float4 nx0 = float4{0.f, 0.f, 0.f, 0.f};
    float4 nx1 = float4{0.f, 0.f, 0.f, 0.f};
    if (q < KC1 - 1) {
      const int nb = ((q + 1) & 1) * 832;
      for (int i = w; i < NT1; i += 4) {
        const _Float16* gp =
            g_wfrag + (((size_t)((q + 1) * NT1 + i)) << 9) + (lane << 3);
        __builtin_amdgcn_global_load_lds(
            (const __attribute__((address_space(1))) void*)gp,
            (__attribute__((address_space(3))) void*)(smemv + nb + i * 64),
            16, 0, 0);
      }
      __builtin_amdgcn_sched_barrier(0);
      const int k0 = (q + 1) * 32 + oct * 8;
      if (k0 + 7 < DIN) {
        nx0 = *reinterpret_cast<const float4*>(xrow + (q + 1) * 32);
        nx1 = *reinterpret_cast<const float4*>(xrow + (q + 1) * 32 + 4);
      }
    }

    float fa[8] = {cur0.x, cur0.y, cur0.z, cur0.w,
                   cur1.x, cur1.y, cur1.z, cur1.w};
    half8 ah;
#pragma unroll
    for (int j = 0; j < 8; ++j) ah[j] = (_Float16)fa[j];

    const int base = (q & 1) * 832;
    __builtin_amdgcn_s_setprio(1);          // T5: favor the MFMA ladder
#pragma unroll
    for (int nt = 0; nt < NT1; ++nt) {
      const half8 bh = smemv[base + nt * 64 + lane];
      acc[nt] = mfma16(ah, bh, acc[nt]);
    }
    __builtin_amdgcn_s_setprio(0);
    cur0 = nx0;
    cur1 = nx1;
  }

  // ---- tanh + proj frags + GEMM-2 (v7 verbatim) ----
  __syncthreads();
  if (lane >= 32) {
    half8 z = {};
    smemv[(24 + w) * 64 + lane] = z;
  }
  _Float16* Pp = reinterpret_cast<_Float16*>(shm);
#pragma unroll
  for (int nt = 0; nt < NT1; ++nt) {
    const int h   = nt * 16 + (lane & 15);
    const int q2  = h >> 5;
    const int lpw = ((h >> 3) & 3) << 4;
    const int jj  = h & 7;
#pragma unroll
    for (int reg = 0; reg < 4; ++reg) {
      const int t = ((lane >> 4) << 2) + reg;
      const float p = fast_tanh(acc[nt][reg]);
      Pp[(size_t)(((q2 * 4 + w) * 64) + lpw + t) * 8 + jj] = (_Float16)p;
    }
  }

  f32x4 s0 = f32x4{0.f, 0.f, 0.f, 0.f};
  f32x4 s1 = f32x4{0.f, 0.f, 0.f, 0.f};
  __builtin_amdgcn_s_setprio(1);            // T5: GEMM-2 cluster
#pragma unroll
  for (int q2 = 0; q2 < KC2; ++q2) {
    const half8 pb = smemv[(q2 * 4 + w) * 64 + lane];
    const half8 c0 = *reinterpret_cast<const half8*>(
        g_cfrag + (((size_t)(q2 * 2)) << 9) + (lane << 3));
    const half8 c1 = *reinterpret_cast<const half8*>(
        g_cfrag + (((size_t)(q2 * 2 + 1)) << 9) + (lane << 3));
    s0 = mfma16(c0, pb, s0);
    s1 = mfma16(c1, pb, s1);
  }
  __builtin_amdgcn_s_setprio(0);

  // ---- biased + masked scores, in registers ----
  const int tok = (w << 4) | (lane & 15);
  const size_t bl = (size_t)b * L_ + l0 + tok;
  const float lamv = lam[0];
  const float mk = (1.0f - mask[bl]) * NEGBIG;
  const int cq = oct << 2;
  const float4 cb0 = *reinterpret_cast<const float4*>(cb + bl * C_ + cq);
  const float4 cb1 = *reinterpret_cast<const float4*>(cb + bl * C_ + 16 + cq);
  float sv[8];
  sv[0] = s0[0] + lamv * cb0.x - mk;  sv[1] = s0[1] + lamv * cb0.y - mk;
  sv[2] = s0[2] + lamv * cb0.z - mk;  sv[3] = s0[3] + lamv * cb0.w - mk;
  sv[4] = s1[0] + lamv * cb1.x - mk;  sv[5] = s1[1] + lamv * cb1.y - mk;
  sv[6] = s1[2] + lamv * cb1.z - mk;  sv[7] = s1[3] + lamv * cb1.w - mk;
  int cidx[8];
#pragma unroll
  for (int r = 0; r < 8; ++r) cidx[r] = (r < 4) ? (cq + r) : (16 + cq + r - 4);

  // ================= Phase 2: split-local softmax =================
  float mx[8];
#pragma unroll
  for (int r = 0; r < 8; ++r) {
    float v = sv[r];
#pragma unroll
    for (int off = 1; off < 16; off <<= 1) v = fmaxf(v, __shfl_xor(v, off));
    mx[r] = v;
  }
  if ((lane & 15) == 0) {
#pragma unroll
    for (int r = 0; r < 8; ++r) redw[w * 32 + cidx[r]] = mx[r];
  }
  __syncthreads();
  if (tid < 32)
    mfin[tid] = fmaxf(fmaxf(redw[tid], redw[32 + tid]),
                      fmaxf(redw[64 + tid], redw[96 + tid]));
  __syncthreads();

  // p = exp(s - m); write P to LDS (r15 swizzle (tok>>3)^(c&7)); den partial
  float pd[8];
#pragma unroll
  for (int r = 0; r < 8; ++r) {
    const float p = __expf(sv[r] - mfin[cidx[r]]);
    pd[r] = p;
    const int c = cidx[r];
    Pl[c * 64 + ((((tok >> 3) ^ (c & 7)) & 7) << 3) + (tok & 7)] = (_Float16)p;
  }
#pragma unroll
  for (int r = 0; r < 8; ++r) {
    float v = pd[r];
#pragma unroll
    for (int off = 1; off < 16; off <<= 1) v += __shfl_xor(v, off);
    pd[r] = v;
  }
  if ((lane & 15) == 0) {
#pragma unroll
    for (int r = 0; r < 8; ++r) redw[w * 32 + cidx[r]] = pd[r];
  }
  __syncthreads();
  if (tid < 32)
    denf[tid] = redw[tid] + redw[32 + tid] + redw[64 + tid] + redw[96 + tid];

  // ================= Phase 3: PV over 2 x 32-token halves =================
  const int ntile0w = (w == 0) ? 0 : (1 + 6 * w);   // 7,6,6,6 of 25 d-tiles
  const int NTWv   = w ? 6 : 7;
  const int n   = lane & 15;

  f32x4 oacc[2][7];
#pragma unroll
  for (int ct = 0; ct < 2; ++ct)
#pragma unroll
    for (int nt = 0; nt < 7; ++nt) oacc[ct][nt] = f32x4{0.f, 0.f, 0.f, 0.f};

  const float* xb = x + ((size_t)b * L_ + l0) * DIN;

  for (int h = 0; h < 2; ++h) {
    __syncthreads();  // prior phase reads of xsw region done
    // stage xT for tokens [h*32, h*32+32): stride-20, proven swizzle
    for (int s = 0; s < 7; ++s) {
      const int i = s * 256 + tid;
      if (i < 1600) {
        const int lp = i / 100, qd = i - lp * 100;
        const float* src = xb + (size_t)(h * 32 + 2 * lp) * DIN + 4 * qd;
        const float4 r0 = *reinterpret_cast<const float4*>(src);
        const float4 r1 = *reinterpret_cast<const float4*>(src + DIN);
#pragma unroll
        for (int k = 0; k < 4; ++k) {
          const int d = 4 * qd + k;
          const int sw = ((d >> 2) ^ (d >> 4)) & 3;
          const int col = (((lp >> 2) ^ sw) << 2) | (lp & 3);
          const _Float16 h0 = (_Float16)r0[k];
          const _Float16 h1 = (_Float16)r1[k];
          unsigned int pk = (unsigned int)__builtin_bit_cast(unsigned short, h0) |
                            ((unsigned int)__builtin_bit_cast(unsigned short, h1) << 16);
          xsw[d * 20 + col] = pk;
        }
      }
    }
    __syncthreads();

    // A-frags from Pl (k = h*32 + oct*8 + j); group = ((4h+oct)^(c&7))&7
    half8 aP[2];
#pragma unroll
    for (int ct = 0; ct < 2; ++ct) {
      const int c = ct * 16 + n;
      aP[ct] = *reinterpret_cast<const half8*>(
          &Pl[c * 64 + (((((h << 2) | oct) ^ (c & 7)) & 7) << 3)]);
    }
    __builtin_amdgcn_s_setprio(1);          // T5: PV cluster
#pragma unroll
    for (int nt = 0; nt < 7; ++nt) {
      if (nt < NTWv) {
        const int d0 = (ntile0w + nt) * 16 + n;
        const int sw = ((d0 >> 2) ^ (d0 >> 4)) & 3;
        const half8 bh = *reinterpret_cast<const half8*>(
            &xsw[d0 * 20 + ((oct ^ sw) << 2)]);
        oacc[0][nt] = mfma16(aP[0], bh, oacc[0][nt]);
        oacc[1][nt] = mfma16(aP[1], bh, oacc[1][nt]);
      }
    }
    __builtin_amdgcn_s_setprio(0);
  }

  // ---- epilogue: O f16 partials + stats ----
  _Float16* Ob = O + ((size_t)(b * NS + split) * C_) * DIN;
#pragma unroll
  for (int nt = 0; nt < 7; ++nt) {
    if (nt < NTWv) {
      const int d = (ntile0w + nt) * 16 + n;
#pragma unroll
      for (int ct = 0; ct < 2; ++ct) {
#pragma unroll
        for (int reg = 0; reg < 4; ++reg) {
          const int c = ct * 16 + oct * 4 + reg;
          Ob[(size_t)c * DIN + d] = (_Float16)oacc[ct][nt][reg];
        }
      }
    }
  }
  if (tid < 32) {
    float* st = stats + (size_t)(b * NS + split) * 64;
    st[tid]      = mfin[tid];
    st[32 + tid] = denf[tid];
  }
}

// ---------------------------------------------------------------------------
// Combine: out[b,c,d] = sum_s e^{m_s-M} O_s[c,d] / sum_s e^{m_s-M} den_s
// ---------------------------------------------------------------------------
__global__ __launch_bounds__(256) void k_combine(
    const _Float16* __restrict__ O, const float* __restrict__ stats,
    float* __restrict__ out)
{
  const int idx = blockIdx.x * 256 + threadIdx.x;   // B*C*50 = 102400
  const int b  = idx / (C_ * 50);
  const int rm = idx - b * (C_ * 50);
  const int c  = rm / 50;
  const int dq = rm - c * 50;

  const float* st = stats + (size_t)b * NS * 64;
  float M = -3.4e38f;
#pragma unroll
  for (int s = 0; s < NS; ++s) M = fmaxf(M, st[s * 64 + c]);
  float wsc[NS];
  float denom = 0.f;
#pragma unroll
  for (int s = 0; s < NS; ++s) {
    const float e = __expf(st[s * 64 + c] - M);
    wsc[s] = e;
    denom += e * st[s * 64 + 32 + c];
  }
  const float inv = 1.0f / denom;

  float o[8] = {};
  const uint4v* Op = reinterpret_cast<const uint4v*>(
      O + ((size_t)(b * NS) * C_ + c) * DIN + dq * 8);
#pragma unroll
  for (int s = 0; s < NS; ++s) {
    const uint4v v = Op[(size_t)s * (C_ * DIN / 8)];
#pragma unroll
    for (int j = 0; j < 4; ++j) {
      o[2 * j]     += wsc[s] * (float)__builtin_bit_cast(_Float16, (unsigned short)(v[j] & 0xffff));
      o[2 * j + 1] += wsc[s] * (float)__builtin_bit_cast(_Float16, (unsigned short)(v[j] >> 16));
    }
  }
  float* op = out + ((size_t)(b * C_) + c) * DIN + dq * 8;
  *reinterpret_cast<float4*>(op)     = float4{o[0]*inv, o[1]*inv, o[2]*inv, o[3]*inv};
  *reinterpret_cast<float4*>(op + 4) = float4{o[4]*inv, o[5]*inv, o[6]*inv, o[7]*inv};
}

// ======================= FALLBACK PATH (r14, proven) =======================
__global__ __launch_bounds__(256, 5) void k_scores(
    const float* __restrict__ x, const float* __restrict__ cb,
    const float* __restrict__ mask, const float* __restrict__ lam,
    float* __restrict__ S)
{
  __shared__ half8 smemv[1792];
  const int tid  = threadIdx.x;
  const int lane = tid & 63;
  const int w    = __builtin_amdgcn_readfirstlane(tid >> 6);
  const int b    = blockIdx.y;
  const int l0   = blockIdx.x * 64;
  const int oct  = lane >> 4;

  f32x4 acc[NT1];
#pragma unroll
  for (int nt = 0; nt < NT1; ++nt) acc[nt] = f32x4{0.f, 0.f, 0.f, 0.f};
  const float* xrow =
      x + ((size_t)b * L_ + l0 + w * 16 + (lane & 15)) * DIN + oct * 8;
  for (int i = w; i < NT1; i += 4) {
    const _Float16* gp = g_wfrag + (((size_t)i) << 9) + (lane << 3);
    __builtin_amdgcn_global_load_lds(
        (const __attribute__((address_space(1))) void*)gp,
        (__attribute__((address_space(3))) void*)(smemv + i * 64), 16, 0, 0);
  }
  __builtin_amdgcn_sched_barrier(0);
  float4 cur0 = *reinterpret_cast<const float4*>(xrow);
  float4 cur1 = *reinterpret_cast<const float4*>(xrow + 4);
#pragma unroll
  for (int q = 0; q < KC1; ++q) {
    asm volatile("s_waitcnt vmcnt(2)\n\ts_barrier" ::: "memory");
    float4 nx0 = float4{0.f, 0.f, 0.f, 0.f};
    float4 nx1 = float4{0.f, 0.f, 0.f, 0.f};
    if (q < KC1 - 1) {
      const int nb = ((q + 1) & 1) * 832;
      for (int i = w; i < NT1; i += 4) {
        const _Float16* gp =
            g_wfrag + (((size_t)((q + 1) * NT1 + i)) << 9) + (lane << 3);
        __builtin_amdgcn_global_load_lds(
            (const __attribute__((address_space(1))) void*)gp,
            (__attribute__((address_space(3))) void*)(smemv + nb + i * 64),
            16, 0, 0);
      }
      __builtin_amdgcn_sched_barrier(0);
      const int k0 = (q + 1) * 32 + oct * 8;
      if (k0 + 7 < DIN) {
        nx0 = *reinterpret_cast<const float4*>(xrow + (q + 1) * 32);
        nx1 = *reinterpret_cast<const float4*>(xrow + (q + 1) * 32 + 4);
      }
    }
    float fa[8] = {cur0.x, cur0.y, cur0.z, cur0.w,
                   cur1.x, cur1.y, cur1.z, cur1.w};
    half8 ah;
#pragma unroll
    for (int j = 0; j < 8; ++j) ah[j] = (_Float16)fa[j];
    const int base = (q & 1) * 832;
#pragma unroll
    for (int nt = 0; nt < NT1; ++nt) {
      const half8 bh = smemv[base + nt * 64 + lane];
      acc[nt] = mfma16(ah, bh, acc[nt]);
    }
    cur0 = nx0; cur1 = nx1;
  }
  __syncthreads();
  if (lane >= 32) { half8 z = {}; smemv[(24 + w) * 64 + lane] = z; }
  _Float16* Pp = reinterpret_cast<_Float16*>(smemv);
#pragma unroll
  for (int nt = 0; nt < NT1; ++nt) {
    const int h = nt * 16 + (lane & 15);
    const int q2 = h >> 5, lpw = ((h >> 3) & 3) << 4, jj = h & 7;
#pragma unroll
    for (int reg = 0; reg < 4; ++reg) {
      const int t = ((lane >> 4) << 2) + reg;
      Pp[(size_t)(((q2 * 4 + w) * 64) + lpw + t) * 8 + jj] =
          (_Float16)fast_tanh(acc[nt][reg]);
    }
  }
  f32x4 s0 = f32x4{0.f, 0.f, 0.f, 0.f};
  f32x4 s1 = f32x4{0.f, 0.f, 0.f, 0.f};
#pragma unroll
  for (int q2 = 0; q2 < KC2; ++q2) {
    const half8 pb = smemv[(q2 * 4 + w) * 64 + lane];
    const half8 c0 = *reinterpret_cast<const half8*>(
        g_cfrag + (((size_t)(q2 * 2)) << 9) + (lane << 3));
    const half8 c1 = *reinterpret_cast<const half8*>(
        g_cfrag + (((size_t)(q2 * 2 + 1)) << 9) + (lane << 3));
    s0 = mfma16(c0, pb, s0);
    s1 = mfma16(c1, pb, s1);
  }
  const int tok = (w << 4) | (lane & 15);
  const size_t bl = (size_t)b * L_ + l0 + tok;
  const float lamv = lam[0];
  const float mk = (1.0f - mask[bl]) * NEGBIG;
  const int cq = (lane >> 4) << 2;
  const float4 cb0 = *reinterpret_cast<const float4*>(cb + bl * C_ + cq);
  const float4 cb1 = *reinterpret_cast<const float4*>(cb + bl * C_ + 16 + cq);
  float* Sp = S + (size_t)b * C_ * L_ + l0 + tok;
  Sp[(size_t)(cq + 0) * L_] = s0[0] + lamv * cb0.x - mk;
  Sp[(size_t)(cq + 1) * L_] = s0[1] + lamv * cb0.y - mk;
  Sp[(size_t)(cq + 2) * L_] = s0[2] + lamv * cb0.z - mk;
  Sp[(size_t)(cq + 3) * L_] = s0[3] + lamv * cb0.w - mk;
  Sp[(size_t)(16 + cq + 0) * L_] = s1[0] + lamv * cb1.x - mk;
  Sp[(size_t)(16 + cq + 1) * L_] = s1[1] + lamv * cb1.y - mk;
  Sp[(size_t)(16 + cq + 2) * L_] = s1[2] + lamv * cb1.z - mk;
  Sp[(size_t)(16 + cq + 3) * L_] = s1[3] + lamv * cb1.w - mk;
}

__global__ __launch_bounds__(256) void k_softmax(float* __restrict__ S,
                                                 _Float16* __restrict__ wh)
{
  const int row = blockIdx.x;
  float* R = S + (size_t)row * L_;
  const int t8 = threadIdx.x * 8;
  const float4 va = *reinterpret_cast<const float4*>(R + t8);
  const float4 vb = *reinterpret_cast<const float4*>(R + t8 + 4);
  float v[8] = {va.x, va.y, va.z, va.w, vb.x, vb.y, vb.z, vb.w};
  float m = -3.4e38f;
#pragma unroll
  for (int j = 0; j < 8; ++j) m = fmaxf(m, v[j]);
#pragma unroll
  for (int o = 32; o > 0; o >>= 1) m = fmaxf(m, __shfl_xor(m, o));
  __shared__ float red[4];
  const int wid = threadIdx.x >> 6;
  if ((threadIdx.x & 63) == 0) red[wid] = m;
  __syncthreads();
  m = fmaxf(fmaxf(red[0], red[1]), fmaxf(red[2], red[3]));
  __syncthreads();
  float s = 0.f;
#pragma unroll
  for (int j = 0; j < 8; ++j) { v[j] = __expf(v[j] - m); s += v[j]; }
#pragma unroll
  for (int o = 32; o > 0; o >>= 1) s += __shfl_xor(s, o);
  if ((threadIdx.x & 63) == 0) red[wid] = s;
  __syncthreads();
  s = red[0] + red[1] + red[2] + red[3];
  const float inv = 1.0f / s;
  if (wh != nullptr) {
    uint4v pk;
#pragma unroll
    for (int p = 0; p < 4; ++p) {
      const _Float16 h0 = (_Float16)(v[2 * p] * inv);
      const _Float16 h1 = (_Float16)(v[2 * p + 1] * inv);
      pk[p] = (unsigned int)__builtin_bit_cast(unsigned short, h0) |
              ((unsigned int)__builtin_bit_cast(unsigned short, h1) << 16);
    }
    *reinterpret_cast<uint4v*>(wh + (size_t)row * L_ + t8) = pk;
  } else {
#pragma unroll
    for (int j = 0; j < 8; ++j) R[t8 + j] = v[j] * inv;
  }
}

__global__ __launch_bounds__(512, 4) void k_out_mfma(
    const float* __restrict__ x, const _Float16* __restrict__ wh,
    _Float16* __restrict__ part)
{
  __shared__ unsigned int xsw[400 * 20];
  __shared__ unsigned int ws16[32][16];
  const int tid  = threadIdx.x;
  const int lane = tid & 63;
  const int w    = __builtin_amdgcn_readfirstlane(tid >> 6);
  const int b    = blockIdx.y;
  const int kq   = blockIdx.x;
  const int l0b  = kq * (L_ / NLC);
  const int ntile0 = (w < 7) ? w * 3 : 21;
  const int NTW    = (w < 7) ? 3 : 4;
  const int n   = lane & 15;
  const int oct = lane >> 4;
  f32x4 acc[4][2];
#pragma unroll
  for (int i = 0; i < 4; ++i) {
    acc[i][0] = f32x4{0.f, 0.f, 0.f, 0.f};
    acc[i][1] = f32x4{0.f, 0.f, 0.f, 0.f};
  }
  const float* xb = x + ((size_t)b * L_ + l0b) * DIN;
  const unsigned int* whb = reinterpret_cast<const unsigned int*>(
      wh + (size_t)b * C_ * L_ + l0b);
  float4 r0[4], r1[4];
  unsigned int wreg;
#pragma unroll
  for (int s = 0; s < 4; ++s) {
    const int i = s * 512 + tid;
    if (s < 3 || i < 1600) {
      const int lp = i / 100, qd = i - lp * 100;
      const float* src = xb + (size_t)(2 * lp) * DIN + 4 * qd;
      r0[s] = *reinterpret_cast<const float4*>(src);
      r1[s] = *reinterpret_cast<const float4*>(src + DIN);
    }
  }
  wreg = whb[((size_t)(tid >> 4) * L_) / 2 + (tid & 15)];
  const int NCH = (L_ / NLC) / 32;
  for (int ch = 0; ch < NCH; ++ch) {
    __syncthreads();
#pragma unroll
    for (int s = 0; s < 4; ++s) {
      const int i = s * 512 + tid;
      if (s < 3 || i < 1600) {
        const int lp = i / 100, qd = i - lp * 100;
#pragma unroll
        for (int k = 0; k < 4; ++k) {
          const int d = 4 * qd + k;
          const int sw = ((d >> 2) ^ (d >> 4)) & 3;
          const int col = (((lp >> 2) ^ sw) << 2) | (lp & 3);
          const _Float16 h0 = (_Float16)r0[s][k];
          const _Float16 h1 = (_Float16)r1[s][k];
          unsigned int pk = (unsigned int)__builtin_bit_cast(unsigned short, h0) |
                            ((unsigned int)__builtin_bit_cast(unsigned short, h1) << 16);
          xsw[d * 20 + col] = pk;
        }
      }
    }
    ws16[tid >> 4][tid & 15] = wreg;
    __syncthreads();
    if (ch + 1 < NCH) {
      const float* xc = xb + (size_t)((ch + 1) * 32) * DIN;
#pragma unroll
      for (int s = 0; s < 4; ++s) {
        const int i = s * 512 + tid;
        if (s < 3 || i < 1600) {
          const int lp = i / 100, qd = i - lp * 100;
          const float* src = xc + (size_t)(2 * lp) * DIN + 4 * qd;
          r0[s] = *reinterpret_cast<const float4*>(src);
          r1[s] = *reinterpret_cast<const float4*>(src + DIN);
        }
      }
      wreg = whb[((size_t)(tid >> 4) * L_ + (ch + 1) * 32) / 2 + (tid & 15)];
    }
    union { uint4v u; half8 h; } a0c, a1c;
    a0c.u = *reinterpret_cast<const uint4v*>(&ws16[n][oct * 4]);
    a1c.u = *reinterpret_cast<const uint4v*>(&ws16[n + 16][oct * 4]);
    const half8 a0 = a0c.h;
    const half8 a1 = a1c.h;
#pragma unroll
    for (int nt = 0; nt < 4; ++nt) {
      if (nt < NTW) {
        const int d0 = (ntile0 + nt) * 16 + n;
        const int sw = ((d0 >> 2) ^ (d0 >> 4)) & 3;
        const half8 bh = *reinterpret_cast<const half8*>(
            &xsw[d0 * 20 + ((oct ^ sw) << 2)]);
        acc[nt][0] = mfma16(a0, bh, acc[nt][0]);
        acc[nt][1] = mfma16(a1, bh, acc[nt][1]);
      }
    }
  }
  _Float16* pb = part + ((size_t)(b * NLC + kq) * C_) * DIN;
#pragma unroll
  for (int nt = 0; nt < 4; ++nt) {
    if (nt < NTW) {
      const int d = (ntile0 + nt) * 16 + n;
#pragma unroll
      for (int mt = 0; mt < 2; ++mt) {
#pragma unroll
        for (int reg = 0; reg < 4; ++reg) {
          const int c = mt * 16 + oct * 4 + reg;
          pb[(size_t)c * DIN + d] = (_Float16)acc[nt][mt][reg];
        }
      }
    }
  }
}

__global__ __launch_bounds__(256) void k_out_reduce(
    const _Float16* __restrict__ part, float* __restrict__ out)
{
  const int idx = blockIdx.x * 256 + threadIdx.x;
  const int per_b = C_ * DIN / 8;
  const int b = idx / per_b;
  const int r = idx - b * per_b;
  const uint4v* p = reinterpret_cast<const uint4v*>(part) +
                    (size_t)b * NLC * per_b + r;
  float s[8] = {};
#pragma unroll
  for (int lc = 0; lc < NLC; ++lc) {
    const uint4v v = p[(size_t)lc * per_b];
#pragma unroll
    for (int j = 0; j < 4; ++j) {
      s[2 * j]     += (float)__builtin_bit_cast(_Float16, (unsigned short)(v[j] & 0xffff));
      s[2 * j + 1] += (float)__builtin_bit_cast(_Float16, (unsigned short)(v[j] >> 16));
    }
  }
  float* o = out + (size_t)idx * 8;
  *reinterpret_cast<float4*>(o)     = float4{s[0], s[1], s[2], s[3]};
  *reinterpret_cast<float4*>(o + 4) = float4{s[4], s[5], s[6], s[7]};
}

extern "C" void kernel_launch(void* const* d_in, const int* in_sizes, int n_in,
                              void* d_out, int out_size, void* d_ws, size_t ws_size,
                              hipStream_t stream)
{
  const float* x    = (const float*)d_in[0];
  const float* cb   = (const float*)d_in[1];
  const float* mask = (const float*)d_in[2];
  const float* Wp   = (const float*)d_in[3];
  const float* ctx  = (const float*)d_in[4];
  const float* lam  = (const float*)d_in[5];
  float* out = (float*)d_out;

  k_prep<<<dim3(KC1 * NT1 + KC2 * MT2), 64, 0, stream>>>(Wp, ctx);

  // fused path: O [B,NS,C,DIN] f16 (52.4 MB) + stats [B,NS,64] f32 (0.5 MB)
  const size_t O_bytes = (size_t)B_ * NS * C_ * DIN * sizeof(_Float16);
  const size_t st_bytes = (size_t)B_ * NS * 64 * sizeof(float);
  if (ws_size >= O_bytes + st_bytes) {
    _Float16* O = (_Float16*)d_ws;
    float* stats = (float*)((char*)d_ws + O_bytes);
    k_fused<<<dim3(NS, B_), 256, 0, stream>>>(x, cb, mask, lam, O, stats);
    k_combine<<<dim3(B_ * C_ * 50 / 256), 256, 0, stream>>>(O, stats, out);
    return;
  }

  // fallback: proven r14 5-kernel path (needs 34.6 MB)
  const size_t part_bytes = (size_t)B_ * NLC * C_ * DIN * sizeof(_Float16);
  float* S = (float*)d_ws;
  _Float16* part = (_Float16*)d_ws;
  _Float16* wh = (_Float16*)((char*)d_ws + part_bytes);
  k_scores<<<dim3(L_ / 64, B_), 256, 0, stream>>>(x, cb, mask, lam, S);
  k_softmax<<<dim3(B_ * C_), 256, 0, stream>>>(S, wh);
  k_out_mfma<<<dim3(NLC, B_), 512, 0, stream>>>(x, wh, part);
  k_out_reduce<<<dim3(B_ * C_ * DIN / 8 / 256), 256, 0, stream>>>(part, out);
}